// Round 7
// baseline (373.428 us; speedup 1.0000x reference)
//
#include <hip/hip_runtime.h>

typedef __attribute__((ext_vector_type(4))) float f32x4;
typedef __attribute__((ext_vector_type(4))) int   i32x4;
typedef __attribute__((ext_vector_type(8))) int   i32x8;

#define MARGIN 0.1f
#define SC1 0x7F7F7F7F   // E8M0 scale bytes = 127 -> 2^0 = 1.0

__device__ __forceinline__ unsigned int pk4(const float4 f) {
    int u = __builtin_amdgcn_cvt_pk_fp8_f32(f.x, f.y, 0, false);
    u = __builtin_amdgcn_cvt_pk_fp8_f32(f.z, f.w, u, true);
    return (unsigned)u;
}
__device__ __forceinline__ uint4 cvtcell(const float4* r) {
    return make_uint4(pk4(r[0]), pk4(r[1]), pk4(r[2]), pk4(r[3]));
}

// Kernel 1: L2-normalize inputs -> fp8 A-frags (K=128 layout, verified R6);
// neg[b] = f32 dot(x, emb[target[b]]).
__global__ __launch_bounds__(256) void prep_kernel(
    const float* __restrict__ inputs, const float* __restrict__ emb,
    const int* __restrict__ target, unsigned char* __restrict__ x_frag,
    float* __restrict__ neg)
{
    const int t = threadIdx.x;
    const int b = blockIdx.x;
    const float2 v = *reinterpret_cast<const float2*>(inputs + (size_t)b * 512 + t * 2);
    const int tgt = target[b];
    const float2 e = *reinterpret_cast<const float2*>(emb + (size_t)tgt * 512 + t * 2);
    float ss = v.x * v.x + v.y * v.y;
    float de = v.x * e.x + v.y * e.y;
    #pragma unroll
    for (int off = 32; off; off >>= 1) {
        ss += __shfl_down(ss, off);
        de += __shfl_down(de, off);
    }
    __shared__ float s_ss[4], s_de[4];
    const int wid = t >> 6, lane = t & 63;
    if (lane == 0) { s_ss[wid] = ss; s_de[wid] = de; }
    __syncthreads();
    const float tss = s_ss[0] + s_ss[1] + s_ss[2] + s_ss[3];
    const float tde = s_de[0] + s_de[1] + s_de[2] + s_de[3];
    const float inv = 1.0f / fmaxf(sqrtf(tss), 1e-12f);
    const int pk = __builtin_amdgcn_cvt_pk_fp8_f32(v.x * inv, v.y * inv, 0, false);
    const int addr = (b >> 4) * 8192 + (t >> 6) * 2048 +
                     (((t >> 4) & 3) * 16 + (b & 15)) * 32 + ((2 * t) & 31);
    *reinterpret_cast<unsigned short*>(x_frag + addr) =
        (unsigned short)(pk & 0xffff);
    if (t == 0) neg[b] = tde * inv;
}

// Kernel 2 (fused): A (x) resident in registers; emb read as f32, converted
// to fp8 in-register (cvt_pk), ds_write'd into double-buffered frag-major LDS.
// T14 schedule: loads for tile j+1 issued during tile j's MFMAs; cvt mid-MFMA;
// short write window between the two barriers. MX MFMA 16x16x128, unit scales.
__global__ __launch_bounds__(512, 2) void gemm_fused_kernel(
    const unsigned char* __restrict__ x_frag, const float* __restrict__ emb,
    const float* __restrict__ neg, float* __restrict__ partials)
{
    __shared__ unsigned char btile[65536];        // 2 x 32 KB double buffer
    const int t = threadIdx.x;
    const int wid = t >> 6, lane = t & 63;
    const int lrow = lane & 15, g = lane >> 4;
    const int nf_w = wid & 3, h_w = wid >> 2;     // staging role of this wave
    const int bx = blockIdx.x;
    const int group = (bx & 7) | ((bx >> 4) << 3);     // 0..127; pair bx,bx+8 same XCD
    const int mhalf = (bx >> 3) & 1;
    const int cnt = (group < 80) ? 16 : 15;            // 80*16 + 48*15 = 2000

    // ---- A prologue: wave's 64 m-rows, full K=512 ----
    i32x8 areg[4][4];                                  // 128 VGPR
    #pragma unroll
    for (int mf = 0; mf < 4; ++mf) {
        const int f = mhalf * 32 + wid * 4 + mf;
        const i32x4* ap = reinterpret_cast<const i32x4*>(
            x_frag + (size_t)f * 8192 + lane * 32);
        #pragma unroll
        for (int kk = 0; kk < 4; ++kk) {
            const i32x4 lo = ap[kk * 128];
            const i32x4 hi = ap[kk * 128 + 1];
            areg[mf][kk] = __builtin_shufflevector(lo, hi, 0, 1, 2, 3, 4, 5, 6, 7);
        }
    }

    // ---- stage tile 0 (f32 -> fp8 -> LDS buf0) ----
    {
        const float4* sp0 = reinterpret_cast<const float4*>(emb) +
            ((size_t)(group * 64 + nf_w * 16 + lrow) * 128 + g * 8 + h_w * 4);
        #pragma unroll
        for (int kk = 0; kk < 4; ++kk) {
            float4 r[4];
            #pragma unroll
            for (int i = 0; i < 4; ++i) r[i] = sp0[kk * 32 + i];
            *reinterpret_cast<uint4*>(
                btile + kk * 8192 + h_w * 4096 + nf_w * 1024 + lane * 16) = cvtcell(r);
        }
    }
    __syncthreads();

    const int rbase = mhalf * 512 + wid * 64 + g * 4;
    float sum = 0.0f;

#define MFMA_KK(kk)                                                           \
    {                                                                         \
        _Pragma("unroll")                                                     \
        for (int nf = 0; nf < 4; ++nf) {                                      \
            const i32x4 lo = *reinterpret_cast<const i32x4*>(                 \
                bb + (kk) * 8192 + nf * 1024);                                \
            const i32x4 hi = *reinterpret_cast<const i32x4*>(                 \
                bb + (kk) * 8192 + nf * 1024 + 4096);                         \
            const i32x8 bfr = __builtin_shufflevector(lo, hi,                 \
                                                      0, 1, 2, 3, 4, 5, 6, 7);\
            _Pragma("unroll")                                                 \
            for (int mf = 0; mf < 4; ++mf)                                    \
                acc[mf][nf] = __builtin_amdgcn_mfma_scale_f32_16x16x128_f8f6f4(\
                    areg[mf][kk], bfr, acc[mf][nf], 0, 0, 0, SC1, 0, SC1);    \
        }                                                                     \
    }

    #pragma unroll 1
    for (int j = 0; j < cnt; ++j) {
        const bool more = (j + 1 < cnt);
        const float4* spn = reinterpret_cast<const float4*>(emb) +
            ((size_t)((group + 128 * (j + 1)) * 64 + nf_w * 16 + lrow) * 128 +
             g * 8 + h_w * 4);

        f32x4 acc[4][4];
        #pragma unroll
        for (int i = 0; i < 4; ++i)
            #pragma unroll
            for (int k = 0; k < 4; ++k) acc[i][k] = (f32x4)(0.0f);

        const unsigned char* bb = btile + (j & 1) * 32768 + lane * 16;

        float4 ra[8];
        if (more) {                                   // issue kk0,kk1 loads early
            #pragma unroll
            for (int c = 0; c < 2; ++c)
                #pragma unroll
                for (int i = 0; i < 4; ++i) ra[c * 4 + i] = spn[c * 32 + i];
        }

        MFMA_KK(0);

        uint4 pk0, pk1, pk2, pk3;
        float4 rb[8];
        if (more) {
            pk0 = cvtcell(ra); pk1 = cvtcell(ra + 4); // consume A, free regs
            #pragma unroll
            for (int c = 0; c < 2; ++c)               // issue kk2,kk3 loads
                #pragma unroll
                for (int i = 0; i < 4; ++i) rb[c * 4 + i] = spn[(2 + c) * 32 + i];
        }

        MFMA_KK(1);
        MFMA_KK(2);
        if (more) { pk2 = cvtcell(rb); pk3 = cvtcell(rb + 4); }
        MFMA_KK(3);

        // ---- fused epilogue: relu(margin + dot - neg[m]) summed ----
        #pragma unroll
        for (int mf = 0; mf < 4; ++mf) {
            const float4 nv = *reinterpret_cast<const float4*>(neg + rbase + mf * 16);
            #pragma unroll
            for (int jj = 0; jj < 4; ++jj) {
                const float thr = (&nv.x)[jj] - MARGIN;
                #pragma unroll
                for (int nf = 0; nf < 4; ++nf)
                    sum += fmaxf(acc[mf][nf][jj] - thr, 0.0f);
            }
        }

        __syncthreads();                              // all waves done reading
        if (more) {
            const int db = ((j + 1) & 1) * 32768 + h_w * 4096 + nf_w * 1024 + lane * 16;
            *reinterpret_cast<uint4*>(btile + db)         = pk0;
            *reinterpret_cast<uint4*>(btile + db + 8192)  = pk1;
            *reinterpret_cast<uint4*>(btile + db + 16384) = pk2;
            *reinterpret_cast<uint4*>(btile + db + 24576) = pk3;
        }
        __syncthreads();                              // writes visible to all
    }

    // ---- block reduction ----
    #pragma unroll
    for (int off = 32; off; off >>= 1) sum += __shfl_down(sum, off);
    float* red = reinterpret_cast<float*>(btile);
    __syncthreads();
    if (lane == 0) red[wid] = sum;
    __syncthreads();
    if (t == 0) {
        float tot = 0.f;
        #pragma unroll
        for (int w = 0; w < 8; ++w) tot += red[w];
        partials[bx] = tot;
    }
}

// Kernel 3: deterministic final reduction of 256 block partials, mean over B.
__global__ __launch_bounds__(256) void reduce_kernel(
    const float* __restrict__ partials, float* __restrict__ out)
{
    float s = partials[threadIdx.x];
    #pragma unroll
    for (int off = 32; off; off >>= 1) s += __shfl_down(s, off);
    __shared__ float red[4];
    const int wid = threadIdx.x >> 6, lane = threadIdx.x & 63;
    if (lane == 0) red[wid] = s;
    __syncthreads();
    if (threadIdx.x == 0)
        out[0] = (red[0] + red[1] + red[2] + red[3]) * (1.0f / 1024.0f);
}

extern "C" void kernel_launch(void* const* d_in, const int* in_sizes, int n_in,
                              void* d_out, int out_size, void* d_ws, size_t ws_size,
                              hipStream_t stream)
{
    const float* inputs = (const float*)d_in[0];
    const float* emb    = (const float*)d_in[1];
    const int*   target = (const int*)d_in[2];
    float* out = (float*)d_out;
    char*  ws  = (char*)d_ws;

    unsigned char* x_frag = (unsigned char*)ws;                     // 512 KB
    float*         neg    = (float*)(ws + 524288);                  // 4 KB
    float*         parts  = (float*)(ws + 528384);                  // 1 KB

    prep_kernel<<<1024, 256, 0, stream>>>(inputs, emb, target, x_frag, neg);
    gemm_fused_kernel<<<256, 512, 0, stream>>>(x_frag, emb, neg, parts);
    reduce_kernel<<<1, 256, 0, stream>>>(parts, out);
}

// Round 8
// 242.255 us; speedup vs baseline: 1.5415x; 1.5415x over previous
//
#include <hip/hip_runtime.h>

typedef __attribute__((ext_vector_type(4))) float f32x4;
typedef __attribute__((ext_vector_type(4))) int   i32x4;
typedef __attribute__((ext_vector_type(8))) int   i32x8;

#define MARGIN 0.1f
#define SC1 0x7F7F7F7F   // E8M0 scale bytes = 127 -> 2^0 = 1.0

__device__ __forceinline__ unsigned int pk4(const float4 f) {
    int u = __builtin_amdgcn_cvt_pk_fp8_f32(f.x, f.y, 0, false);
    u = __builtin_amdgcn_cvt_pk_fp8_f32(f.z, f.w, u, true);
    return (unsigned)u;
}
__device__ __forceinline__ uint4 cvtcell(const float4* r) {
    return make_uint4(pk4(r[0]), pk4(r[1]), pk4(r[2]), pk4(r[3]));
}

// Kernel 1: L2-normalize inputs -> fp8 A-frags (K=128 layout, verified R6);
// neg[b] = f32 dot(x, emb[target[b]]).
__global__ __launch_bounds__(256) void prep_kernel(
    const float* __restrict__ inputs, const float* __restrict__ emb,
    const int* __restrict__ target, unsigned char* __restrict__ x_frag,
    float* __restrict__ neg)
{
    const int t = threadIdx.x;
    const int b = blockIdx.x;
    const float2 v = *reinterpret_cast<const float2*>(inputs + (size_t)b * 512 + t * 2);
    const int tgt = target[b];
    const float2 e = *reinterpret_cast<const float2*>(emb + (size_t)tgt * 512 + t * 2);
    float ss = v.x * v.x + v.y * v.y;
    float de = v.x * e.x + v.y * e.y;
    #pragma unroll
    for (int off = 32; off; off >>= 1) {
        ss += __shfl_down(ss, off);
        de += __shfl_down(de, off);
    }
    __shared__ float s_ss[4], s_de[4];
    const int wid = t >> 6, lane = t & 63;
    if (lane == 0) { s_ss[wid] = ss; s_de[wid] = de; }
    __syncthreads();
    const float tss = s_ss[0] + s_ss[1] + s_ss[2] + s_ss[3];
    const float tde = s_de[0] + s_de[1] + s_de[2] + s_de[3];
    const float inv = 1.0f / fmaxf(sqrtf(tss), 1e-12f);
    const int pk = __builtin_amdgcn_cvt_pk_fp8_f32(v.x * inv, v.y * inv, 0, false);
    const int addr = (b >> 4) * 8192 + (t >> 6) * 2048 +
                     (((t >> 4) & 3) * 16 + (b & 15)) * 32 + ((2 * t) & 31);
    *reinterpret_cast<unsigned short*>(x_frag + addr) =
        (unsigned short)(pk & 0xffff);
    if (t == 0) neg[b] = tde * inv;
}

// Kernel 2 (fused): A (x) resident in registers; emb read as f32, converted
// to fp8 in-register (cvt_pk), ds_write'd immediately (regs freed) into the
// other half of a double-buffered frag-major LDS tile. ONE barrier per tile.
// No launch_bounds occupancy arg -> no 128-reg cap -> no spill.
__global__ __launch_bounds__(512) void gemm_fused_kernel(
    const unsigned char* __restrict__ x_frag, const float* __restrict__ emb,
    const float* __restrict__ neg, float* __restrict__ partials)
{
    __shared__ unsigned char btile[65536];        // 2 x 32 KB double buffer
    const int t = threadIdx.x;
    const int wid = t >> 6, lane = t & 63;
    const int lrow = lane & 15, g = lane >> 4;
    const int nf_w = wid & 3, h_w = wid >> 2;     // staging role of this wave
    const int bx = blockIdx.x;
    const int group = (bx & 7) | ((bx >> 4) << 3);     // bx, bx+8 same group+XCD
    const int mhalf = (bx >> 3) & 1;
    const int cnt = (group < 80) ? 16 : 15;            // 80*16 + 48*15 = 2000

    // ---- A prologue: wave's 64 m-rows, full K=512 ----
    i32x8 areg[4][4];                                  // 128 VGPR
    #pragma unroll
    for (int mf = 0; mf < 4; ++mf) {
        const int f = mhalf * 32 + wid * 4 + mf;
        const i32x4* ap = reinterpret_cast<const i32x4*>(
            x_frag + (size_t)f * 8192 + lane * 32);
        #pragma unroll
        for (int kk = 0; kk < 4; ++kk) {
            const i32x4 lo = ap[kk * 128];
            const i32x4 hi = ap[kk * 128 + 1];
            areg[mf][kk] = __builtin_shufflevector(lo, hi, 0, 1, 2, 3, 4, 5, 6, 7);
        }
    }

    // ---- stage tile 0 (f32 -> fp8 -> LDS buf0) ----
    {
        const float4* sp0 = reinterpret_cast<const float4*>(emb) +
            ((size_t)(group * 64 + nf_w * 16 + lrow) * 128 + g * 8 + h_w * 4);
        #pragma unroll
        for (int kk = 0; kk < 4; ++kk) {
            float4 r[4];
            #pragma unroll
            for (int i = 0; i < 4; ++i) r[i] = sp0[kk * 32 + i];
            *reinterpret_cast<uint4*>(
                btile + kk * 8192 + h_w * 4096 + nf_w * 1024 + lane * 16) = cvtcell(r);
        }
    }
    __syncthreads();

    const int rbase = mhalf * 512 + wid * 64 + g * 4;
    float sum = 0.0f;

#define MFMA_KK(kk)                                                           \
    {                                                                         \
        _Pragma("unroll")                                                     \
        for (int nf = 0; nf < 4; ++nf) {                                      \
            const i32x4 lo = *reinterpret_cast<const i32x4*>(                 \
                bb + (kk) * 8192 + nf * 1024);                                \
            const i32x4 hi = *reinterpret_cast<const i32x4*>(                 \
                bb + (kk) * 8192 + nf * 1024 + 4096);                         \
            const i32x8 bfr = __builtin_shufflevector(lo, hi,                 \
                                                      0, 1, 2, 3, 4, 5, 6, 7);\
            _Pragma("unroll")                                                 \
            for (int mf = 0; mf < 4; ++mf)                                    \
                acc[mf][nf] = __builtin_amdgcn_mfma_scale_f32_16x16x128_f8f6f4(\
                    areg[mf][kk], bfr, acc[mf][nf], 0, 0, 0, SC1, 0, SC1);    \
        }                                                                     \
    }
#define LOADQ(dst, q)                                                         \
    {                                                                         \
        _Pragma("unroll")                                                     \
        for (int i = 0; i < 4; ++i) dst[i] = spn[(q) * 32 + i];               \
    }
// write quarter q of next tile (to buf[(j+1)&1]) -- race-free anywhere in iter j
#define WRITEQ(src, q)                                                        \
    *reinterpret_cast<uint4*>(btile + ((j + 1) & 1) * 32768 + (q) * 8192 +    \
                              h_w * 4096 + nf_w * 1024 + lane * 16) = cvtcell(src);

    #pragma unroll 1
    for (int j = 0; j < cnt; ++j) {
        const bool more = (j + 1 < cnt);
        const float4* spn = reinterpret_cast<const float4*>(emb) +
            ((size_t)((group + 128 * (j + 1)) * 64 + nf_w * 16 + lrow) * 128 +
             g * 8 + h_w * 4);

        f32x4 acc[4][4];
        #pragma unroll
        for (int i = 0; i < 4; ++i)
            #pragma unroll
            for (int k = 0; k < 4; ++k) acc[i][k] = (f32x4)(0.0f);

        const unsigned char* bb = btile + (j & 1) * 32768 + lane * 16;

        float4 ra[4], rb[4];
        if (more) { LOADQ(ra, 0); LOADQ(rb, 1); }     // 2 quarters in flight
        MFMA_KK(0);
        if (more) { WRITEQ(ra, 0); LOADQ(ra, 2); }    // cvt+write, reuse regs
        MFMA_KK(1);
        if (more) { WRITEQ(rb, 1); LOADQ(rb, 3); }
        MFMA_KK(2);
        if (more) { WRITEQ(ra, 2); }
        MFMA_KK(3);
        if (more) { WRITEQ(rb, 3); }

        // ---- fused epilogue: relu(margin + dot - neg[m]) summed ----
        #pragma unroll
        for (int mf = 0; mf < 4; ++mf) {
            const float4 nv = *reinterpret_cast<const float4*>(neg + rbase + mf * 16);
            #pragma unroll
            for (int jj = 0; jj < 4; ++jj) {
                const float thr = (&nv.x)[jj] - MARGIN;
                #pragma unroll
                for (int nf = 0; nf < 4; ++nf)
                    sum += fmaxf(acc[mf][nf][jj] - thr, 0.0f);
            }
        }

        __syncthreads();          // next-tile writes done + this-tile reads done
    }

    // ---- block reduction ----
    #pragma unroll
    for (int off = 32; off; off >>= 1) sum += __shfl_down(sum, off);
    float* red = reinterpret_cast<float*>(btile);
    if (lane == 0) red[wid] = sum;
    __syncthreads();
    if (t == 0) {
        float tot = 0.f;
        #pragma unroll
        for (int w = 0; w < 8; ++w) tot += red[w];
        partials[bx] = tot;
    }
}

// Kernel 3: deterministic final reduction of 256 block partials, mean over B.
__global__ __launch_bounds__(256) void reduce_kernel(
    const float* __restrict__ partials, float* __restrict__ out)
{
    float s = partials[threadIdx.x];
    #pragma unroll
    for (int off = 32; off; off >>= 1) s += __shfl_down(s, off);
    __shared__ float red[4];
    const int wid = threadIdx.x >> 6, lane = threadIdx.x & 63;
    if (lane == 0) red[wid] = s;
    __syncthreads();
    if (threadIdx.x == 0)
        out[0] = (red[0] + red[1] + red[2] + red[3]) * (1.0f / 1024.0f);
}

extern "C" void kernel_launch(void* const* d_in, const int* in_sizes, int n_in,
                              void* d_out, int out_size, void* d_ws, size_t ws_size,
                              hipStream_t stream)
{
    const float* inputs = (const float*)d_in[0];
    const float* emb    = (const float*)d_in[1];
    const int*   target = (const int*)d_in[2];
    float* out = (float*)d_out;
    char*  ws  = (char*)d_ws;

    unsigned char* x_frag = (unsigned char*)ws;                     // 512 KB
    float*         neg    = (float*)(ws + 524288);                  // 4 KB
    float*         parts  = (float*)(ws + 528384);                  // 1 KB

    prep_kernel<<<1024, 256, 0, stream>>>(inputs, emb, target, x_frag, neg);
    gemm_fused_kernel<<<256, 512, 0, stream>>>(x_frag, emb, neg, parts);
    reduce_kernel<<<1, 256, 0, stream>>>(parts, out);
}